// Round 1
// baseline (201.760 us; speedup 1.0000x reference)
//
#include <hip/hip_runtime.h>

// ---------------------------------------------------------------------------
// QuaternionLinear == one dense GEMM: out[M,N] = x[M,K] @ W_eff[N,K]^T + bias
//   M = 16384 (B*S), N = 2048 (OUT_F), K = 2048 (IN_F)
//   W_eff[4q+co][4p+ci] = sign(co,ci) * w_{comp(co,ci)}[q][p]  (table above)
// Pipeline: cvt_x (fp32->bf16, ws) ; pack_w (build W_eff bf16, ws) ; qgemm.
// ---------------------------------------------------------------------------

typedef unsigned short u16;
typedef __bf16 bf16x8 __attribute__((ext_vector_type(8)));
typedef float f32x4 __attribute__((ext_vector_type(4)));

#define QM 16384
#define QN 2048
#define QK 2048

// RNE float -> bf16 (bit trick; NaN irrelevant for this data)
__device__ __forceinline__ u16 f2bf(float f) {
    union { float f; unsigned u; } v;
    v.f = f;
    unsigned r = v.u + 0x7FFFu + ((v.u >> 16) & 1u);
    return (u16)(r >> 16);
}

// async global->LDS, 16 bytes/lane. LDS dest = wave-uniform base + lane*16.
__device__ __forceinline__ void async_copy16(const u16* g, u16* l) {
    __builtin_amdgcn_global_load_lds(
        (const __attribute__((address_space(1))) void*)g,
        (__attribute__((address_space(3))) void*)l,
        16, 0, 0);
}

// ---------------------------------------------------------------------------
// Kernel 1: x fp32 -> bf16 (vectorized)
// ---------------------------------------------------------------------------
__global__ void cvt_x_kernel(const float* __restrict__ x, u16* __restrict__ y, int n4) {
    for (int i = blockIdx.x * blockDim.x + threadIdx.x; i < n4; i += gridDim.x * blockDim.x) {
        float4 v = reinterpret_cast<const float4*>(x)[i];
        ushort4 o;
        o.x = f2bf(v.x); o.y = f2bf(v.y); o.z = f2bf(v.z); o.w = f2bf(v.w);
        reinterpret_cast<ushort4*>(y)[i] = o;
    }
}

// ---------------------------------------------------------------------------
// Kernel 2: build W_eff (N=2048 x K=2048, row-major, bf16)
// one thread per (n, p): writes 4 consecutive k (ci = 0..3)
// ---------------------------------------------------------------------------
__global__ void pack_w_kernel(const float* __restrict__ wr, const float* __restrict__ wi,
                              const float* __restrict__ wj, const float* __restrict__ wk,
                              u16* __restrict__ W) {
    int i = blockIdx.x * blockDim.x + threadIdx.x; // [0, 2048*512)
    if (i >= QN * (QK / 4)) return;
    int n = i >> 9;          // output row
    int p = i & 511;         // input quaternion index
    int q = n >> 2, co = n & 3;
    int base = (q << 9) + p; // w[q][p], IQ = 512
    float r  = wr[base], ii = wi[base], jj = wj[base], kk = wk[base];
    float e0, e1, e2, e3;
    if      (co == 0) { e0 = r;  e1 = -ii; e2 = -jj; e3 = -kk; }
    else if (co == 1) { e0 = ii; e1 = r;   e2 = -jj; e3 = kk;  }
    else if (co == 2) { e0 = jj; e1 = ii;  e2 = r;   e3 = -kk; }
    else              { e0 = kk; e1 = -ii; e2 = jj;  e3 = r;   }
    ushort4 o;
    o.x = f2bf(e0); o.y = f2bf(e1); o.z = f2bf(e2); o.w = f2bf(e3);
    reinterpret_cast<ushort4*>(W)[(n << 9) + p] = o;
}

// ---------------------------------------------------------------------------
// Kernel 3: bf16 GEMM, C = A(M,K) * B(N,K)^T + bias  (m97 structure)
//   128x128 tile, BK=64, 4 waves (2x2), 4x4 16x16x32 MFMA frags per wave.
//   global_load_lds width=16, chunk-XOR swizzle (both-sides): physical chunk
//   (r, cp) holds logical (r, cp ^ (r&7)); reads XOR the same way.
// ---------------------------------------------------------------------------
__global__ __launch_bounds__(256) void qgemm_kernel(const u16* __restrict__ A,
                                                    const u16* __restrict__ B,
                                                    const float* __restrict__ bias,
                                                    float* __restrict__ C) {
    __shared__ u16 tA[128 * 64]; // 16 KB
    __shared__ u16 tB[128 * 64]; // 16 KB

    const int bid = blockIdx.x;
    const int nwg = gridDim.x;          // 2048, % 8 == 0 -> simple XCD swizzle ok
    const int cpx = nwg >> 3;
    const int swz = (bid & 7) * cpx + (bid >> 3);
    const int bm = swz >> 4;            // 128 m-tiles
    const int bn = swz & 15;            // 16 n-tiles

    const int tid  = threadIdx.x;
    const int wid  = tid >> 6;
    const int lane = tid & 63;
    const int wm = wid >> 1, wn = wid & 1;
    const int lr = lane & 15, lg = lane >> 4;

    const u16* Asrc = A + (size_t)bm * (128 * QK);
    const u16* Bsrc = B + (size_t)bn * (128 * QK);

    f32x4 acc[4][4];
#pragma unroll
    for (int i = 0; i < 4; ++i)
#pragma unroll
        for (int j = 0; j < 4; ++j)
            acc[i][j] = (f32x4){0.f, 0.f, 0.f, 0.f};

    // staging addressing: 1024 chunks of 16B per tile; wave w iter t covers
    // chunks [(w*4+t)*64, +64). physical chunk ch=(r,cp) sources logical col
    // cl = cp ^ (r&7)  (involution -> read side applies the same XOR)
    int srow[4], scol[4];
#pragma unroll
    for (int t = 0; t < 4; ++t) {
        int ch = ((wid << 2) + t) * 64 + lane;
        srow[t] = ch >> 3;
        scol[t] = ((ch & 7) ^ (srow[t] & 7)) << 3; // element offset in row
    }

    for (int kt = 0; kt < QK / 64; ++kt) {
        const int k0 = kt * 64;
#pragma unroll
        for (int t = 0; t < 4; ++t) {
            const size_t goff = (size_t)srow[t] * QK + k0 + scol[t];
            u16* lbase = ((wid << 2) + t) * 512 + (u16*)nullptr; // offset calc below
            async_copy16(Asrc + goff, tA + ((wid << 2) + t) * 512);
            async_copy16(Bsrc + goff, tB + ((wid << 2) + t) * 512);
            (void)lbase;
        }
        __syncthreads();
#pragma unroll
        for (int ks = 0; ks < 2; ++ks) {
            bf16x8 af[4], bfr[4];
#pragma unroll
            for (int f = 0; f < 4; ++f) {
                const int ra = wm * 64 + f * 16 + lr;
                const int ca = (ks * 4 + lg) ^ (ra & 7);
                af[f] = *(const bf16x8*)&tA[(ra * 8 + ca) * 8];
                const int rb = wn * 64 + f * 16 + lr;
                const int cb = (ks * 4 + lg) ^ (rb & 7);
                bfr[f] = *(const bf16x8*)&tB[(rb * 8 + cb) * 8];
            }
#pragma unroll
            for (int i = 0; i < 4; ++i)
#pragma unroll
                for (int j = 0; j < 4; ++j)
                    acc[i][j] = __builtin_amdgcn_mfma_f32_16x16x32_bf16(af[i], bfr[j], acc[i][j], 0, 0, 0);
        }
        __syncthreads();
    }

    // epilogue: C/D layout col = lane&15, row = (lane>>4)*4 + reg
    const int colbase = bn * 128 + wn * 64;
    float bsv[4];
#pragma unroll
    for (int fn = 0; fn < 4; ++fn) bsv[fn] = bias[colbase + fn * 16 + lr];
    float* Cb = C + (size_t)(bm * 128 + wm * 64) * QN + colbase;
#pragma unroll
    for (int fm = 0; fm < 4; ++fm)
#pragma unroll
        for (int fn = 0; fn < 4; ++fn)
#pragma unroll
            for (int v = 0; v < 4; ++v)
                Cb[(size_t)(fm * 16 + lg * 4 + v) * QN + fn * 16 + lr] = acc[fm][fn][v] + bsv[fn];
}

// ---------------------------------------------------------------------------
extern "C" void kernel_launch(void* const* d_in, const int* in_sizes, int n_in,
                              void* d_out, int out_size, void* d_ws, size_t ws_size,
                              hipStream_t stream) {
    const float* x    = (const float*)d_in[0];
    const float* wr   = (const float*)d_in[1];
    const float* wi   = (const float*)d_in[2];
    const float* wj   = (const float*)d_in[3];
    const float* wk   = (const float*)d_in[4];
    const float* bias = (const float*)d_in[5];
    float* out = (float*)d_out;

    // workspace: [ x_bf16 : 64 MB ][ W_eff bf16 : 8 MB ]
    u16* xb = (u16*)d_ws;
    u16* wb = (u16*)((char*)d_ws + (size_t)QM * QK * 2);

    cvt_x_kernel<<<4096, 256, 0, stream>>>(x, xb, (QM * QK) / 4);
    pack_w_kernel<<<4096, 256, 0, stream>>>(wr, wi, wj, wk, wb);
    qgemm_kernel<<<2048, 256, 0, stream>>>(xb, wb, bias, out);
}

// Round 2
// 169.503 us; speedup vs baseline: 1.1903x; 1.1903x over previous
//
#include <hip/hip_runtime.h>

// ---------------------------------------------------------------------------
// QuaternionLinear == one dense GEMM: out[M,N] = x[M,K] @ W_eff[N,K]^T + bias
//   M = 16384 (B*S), N = 2048 (OUT_F), K = 2048 (IN_F)
// Pipeline: cvt_x (fp32->bf16) ; pack_w (build W_eff bf16) ; qgemm (8-phase).
// qgemm: 256x256 tile, BK=64, 8 waves (2x4), per-wave 128x64, 16x16x32 MFMA,
// double-buffered LDS (128 KB), chunk-XOR swizzle (T2), counted vmcnt(4)
// (T3/T4), setprio around MFMA clusters (T5), XCD-bijective block swizzle (T1).
// ---------------------------------------------------------------------------

typedef unsigned short u16;
typedef __bf16 bf16x8 __attribute__((ext_vector_type(8)));
typedef float f32x4 __attribute__((ext_vector_type(4)));

#define QM 16384
#define QN 2048
#define QK 2048

__device__ __forceinline__ u16 f2bf(float f) {
    union { float f; unsigned u; } v;
    v.f = f;
    unsigned r = v.u + 0x7FFFu + ((v.u >> 16) & 1u);
    return (u16)(r >> 16);
}

__device__ __forceinline__ void async_copy16(const u16* g, u16* l) {
    __builtin_amdgcn_global_load_lds(
        (const __attribute__((address_space(1))) void*)g,
        (__attribute__((address_space(3))) void*)l,
        16, 0, 0);
}

// ---------------------------------------------------------------------------
__global__ void cvt_x_kernel(const float* __restrict__ x, u16* __restrict__ y, int n4) {
    for (int i = blockIdx.x * blockDim.x + threadIdx.x; i < n4; i += gridDim.x * blockDim.x) {
        float4 v = reinterpret_cast<const float4*>(x)[i];
        ushort4 o;
        o.x = f2bf(v.x); o.y = f2bf(v.y); o.z = f2bf(v.z); o.w = f2bf(v.w);
        reinterpret_cast<ushort4*>(y)[i] = o;
    }
}

// ---------------------------------------------------------------------------
__global__ void pack_w_kernel(const float* __restrict__ wr, const float* __restrict__ wi,
                              const float* __restrict__ wj, const float* __restrict__ wk,
                              u16* __restrict__ W) {
    int i = blockIdx.x * blockDim.x + threadIdx.x;
    if (i >= QN * (QK / 4)) return;
    int n = i >> 9;
    int p = i & 511;
    int q = n >> 2, co = n & 3;
    int base = (q << 9) + p;
    float r  = wr[base], ii = wi[base], jj = wj[base], kk = wk[base];
    float e0, e1, e2, e3;
    if      (co == 0) { e0 = r;  e1 = -ii; e2 = -jj; e3 = -kk; }
    else if (co == 1) { e0 = ii; e1 = r;   e2 = -jj; e3 = kk;  }
    else if (co == 2) { e0 = jj; e1 = ii;  e2 = r;   e3 = -kk; }
    else              { e0 = kk; e1 = -ii; e2 = jj;  e3 = r;   }
    ushort4 o;
    o.x = f2bf(e0); o.y = f2bf(e1); o.z = f2bf(e2); o.w = f2bf(e3);
    reinterpret_cast<ushort4*>(W)[(n << 9) + p] = o;
}

// ---------------------------------------------------------------------------
// 8-phase 256^2 GEMM.
// LDS layout (u16 elems): L[b*32768 + mat*16384 + row*64 + chunkswz*8]
//   physical 16B-chunk (r, cp) holds logical (r, cp ^ (r&7))   [involution]
// Stage schedule per K-tile t (4 phases), proven race-free:
//   ph0: reads(B all + A q0) ; stage (t+1, A half0) -> buf[t&1 ^ 1]
//   ph1: reads(A q1)         ; stage (t+1, A half1) -> buf[t&1 ^ 1]
//   ph2: reads(A q2)         ; stage (t+2, B half0) -> buf[t&1]    (B reads of
//   ph3: reads(A q3)         ; stage (t+2, B half1) -> buf[t&1]     buf done @ph0)
//   each phase: barrier; lgkmcnt(0); setprio(1); 16 MFMA; setprio(0); barrier
//   end of ph3: s_waitcnt vmcnt(4) before the trailing barrier
//     -> guarantees tile t+1 (A halves from this tile + B halves from last
//        tile) fully resident; only (t+2,B0/B1) = 4 loads stay in flight.
// ---------------------------------------------------------------------------
__global__ __launch_bounds__(512, 2) void qgemm_kernel(const u16* __restrict__ A,
                                                       const u16* __restrict__ B,
                                                       const float* __restrict__ bias,
                                                       float* __restrict__ C) {
    __shared__ __align__(16) u16 L[2 * 32768];  // 128 KB

    const int bid = blockIdx.x;                 // 512 blocks, %8==0
    const int swz = (bid & 7) * 64 + (bid >> 3);
    const int bm = swz >> 3;                    // 0..63
    const int bn = swz & 7;                     // 0..7

    const int tid = threadIdx.x;
    const int wid = tid >> 6, lane = tid & 63;
    const int wm = wid >> 2, wn = wid & 3;
    const int lr = lane & 15, lg = lane >> 4;

    const u16* Asrc = A + (size_t)bm * 256 * QK;
    const u16* Bsrc = B + (size_t)bn * 256 * QK;

    // staging geometry: half-tile = 128 rows x 64 cols = 1024 chunks of 16B.
    // thread covers chunks {tid, 512+tid}; both share the same swizzled col.
    const int rA  = tid >> 3;                        // 0..63
    const int clA = ((tid & 7) ^ (rA & 7)) << 3;     // element col (swizzled src)
    const size_t soff = (size_t)rA * QK + clA;

    f32x4 acc[8][4];
#pragma unroll
    for (int i = 0; i < 8; ++i)
#pragma unroll
        for (int j = 0; j < 4; ++j)
            acc[i][j] = (f32x4){0.f, 0.f, 0.f, 0.f};

    // stage one half-tile: src = matrix base + half offset, lbase = LDS elem base
    auto stage = [&](const u16* src, int lbase, int k0) {
#pragma unroll
        for (int o = 0; o < 2; ++o)
            async_copy16(src + (size_t)(o * 64) * QK + k0 + soff,
                         &L[lbase + o * 4096 + wid * 512]);   // wave-uniform dst
    };

    // prologue: tile0 {A0,A1,B0,B1}, tile1 {B0,B1}
    stage(Asrc,            0,                 0);
    stage(Asrc + 128 * QK, 8192,              0);
    stage(Bsrc,            16384,             0);
    stage(Bsrc + 128 * QK, 16384 + 8192,      0);
    stage(Bsrc,            32768 + 16384,        64);
    stage(Bsrc + 128 * QK, 32768 + 16384 + 8192, 64);
    asm volatile("s_waitcnt vmcnt(4)" ::: "memory");   // tile0 resident
    __builtin_amdgcn_s_barrier();

    bf16x8 bfr[4][2];
    for (int t = 0; t < 32; ++t) {
        const int b = t & 1;
        const u16* LA = &L[b * 32768];
        const u16* LB = LA + 16384;
        const int tw1 = (t + 1) & 31, tw2 = (t + 2) & 31;

#pragma unroll
        for (int q = 0; q < 4; ++q) {
            if (q == 0) {
#pragma unroll
                for (int nf = 0; nf < 4; ++nf)
#pragma unroll
                    for (int ks = 0; ks < 2; ++ks) {
                        const int r = wn * 64 + nf * 16 + lr;
                        const int c = ((ks * 4 + lg) ^ (r & 7)) << 3;
                        bfr[nf][ks] = *(const bf16x8*)&LB[r * 64 + c];
                    }
            }
            bf16x8 af[2][2];
#pragma unroll
            for (int f = 0; f < 2; ++f)
#pragma unroll
                for (int ks = 0; ks < 2; ++ks) {
                    const int r = wm * 128 + (q * 2 + f) * 16 + lr;
                    const int c = ((ks * 4 + lg) ^ (r & 7)) << 3;
                    af[f][ks] = *(const bf16x8*)&LA[r * 64 + c];
                }

            if (q == 0)      stage(Asrc,            (tw1 & 1) * 32768,                tw1 * 64);
            else if (q == 1) stage(Asrc + 128 * QK, (tw1 & 1) * 32768 + 8192,         tw1 * 64);
            else if (q == 2) stage(Bsrc,            (tw2 & 1) * 32768 + 16384,        tw2 * 64);
            else             stage(Bsrc + 128 * QK, (tw2 & 1) * 32768 + 16384 + 8192, tw2 * 64);

            __builtin_amdgcn_s_barrier();
            asm volatile("s_waitcnt lgkmcnt(0)" ::: "memory");
            __builtin_amdgcn_sched_barrier(0);
            __builtin_amdgcn_s_setprio(1);
#pragma unroll
            for (int f = 0; f < 2; ++f)
#pragma unroll
                for (int nf = 0; nf < 4; ++nf)
#pragma unroll
                    for (int ks = 0; ks < 2; ++ks)
                        acc[q * 2 + f][nf] = __builtin_amdgcn_mfma_f32_16x16x32_bf16(
                            af[f][ks], bfr[nf][ks], acc[q * 2 + f][nf], 0, 0, 0);
            __builtin_amdgcn_s_setprio(0);
            if (q == 3) asm volatile("s_waitcnt vmcnt(4)" ::: "memory");
            __builtin_amdgcn_s_barrier();
        }
    }

    // epilogue: C/D layout col = lane&15, row = (lane>>4)*4 + reg
    const int colbase = bn * 256 + wn * 64;
    const int rowbase = bm * 256 + wm * 128;
    float bsv[4];
#pragma unroll
    for (int nf = 0; nf < 4; ++nf) bsv[nf] = bias[colbase + nf * 16 + lr];
    float* Cb = C + (size_t)rowbase * QN + colbase;
#pragma unroll
    for (int mf = 0; mf < 8; ++mf)
#pragma unroll
        for (int nf = 0; nf < 4; ++nf)
#pragma unroll
            for (int v = 0; v < 4; ++v)
                Cb[(size_t)(mf * 16 + lg * 4 + v) * QN + nf * 16 + lr] = acc[mf][nf][v] + bsv[nf];
}

// ---------------------------------------------------------------------------
extern "C" void kernel_launch(void* const* d_in, const int* in_sizes, int n_in,
                              void* d_out, int out_size, void* d_ws, size_t ws_size,
                              hipStream_t stream) {
    const float* x    = (const float*)d_in[0];
    const float* wr   = (const float*)d_in[1];
    const float* wi   = (const float*)d_in[2];
    const float* wj   = (const float*)d_in[3];
    const float* wk   = (const float*)d_in[4];
    const float* bias = (const float*)d_in[5];
    float* out = (float*)d_out;

    u16* xb = (u16*)d_ws;                                   // 64 MB
    u16* wb = (u16*)((char*)d_ws + (size_t)QM * QK * 2);    // 8 MB

    cvt_x_kernel<<<4096, 256, 0, stream>>>(x, xb, (QM * QK) / 4);
    pack_w_kernel<<<4096, 256, 0, stream>>>(wr, wi, wj, wk, wb);
    qgemm_kernel<<<512, 512, 0, stream>>>(xb, wb, bias, out);
}

// Round 3
// 168.981 us; speedup vs baseline: 1.1940x; 1.0031x over previous
//
#include <hip/hip_runtime.h>

// ---------------------------------------------------------------------------
// QuaternionLinear == one dense GEMM: out[M,N] = x[M,K] @ W_eff[N,K]^T + bias
//   M = 16384 (B*S), N = 2048 (OUT_F), K = 2048 (IN_F)
// Pipeline: cvt_x (fp32->bf16) ; pack_w (build W_eff bf16) ; qgemm (8-phase).
// qgemm: 256x256 tile, BK=64, 8 waves (2x4), per-wave 128x64, 16x16x32 MFMA,
// double-buffered LDS (128 KB), chunk-XOR swizzle (T2), counted vmcnt(4)
// (T3/T4), setprio (T5), XCD swizzle (T1). Phases = (k-slice, m-half)
// quadrants with balanced 8/8/4/4 ds_read pressure (B[ks1] read one phase
// ahead of use so no 12-read lgkm spike).
// ---------------------------------------------------------------------------

typedef unsigned short u16;
typedef __bf16 bf16x8 __attribute__((ext_vector_type(8)));
typedef float f32x4 __attribute__((ext_vector_type(4)));

#define QM 16384
#define QN 2048
#define QK 2048

__device__ __forceinline__ u16 f2bf(float f) {
    union { float f; unsigned u; } v;
    v.f = f;
    unsigned r = v.u + 0x7FFFu + ((v.u >> 16) & 1u);
    return (u16)(r >> 16);
}

__device__ __forceinline__ void async_copy16(const u16* g, u16* l) {
    __builtin_amdgcn_global_load_lds(
        (const __attribute__((address_space(1))) void*)g,
        (__attribute__((address_space(3))) void*)l,
        16, 0, 0);
}

// ---------------------------------------------------------------------------
__global__ void cvt_x_kernel(const float* __restrict__ x, u16* __restrict__ y, int n4) {
    for (int i = blockIdx.x * blockDim.x + threadIdx.x; i < n4; i += gridDim.x * blockDim.x) {
        float4 v = reinterpret_cast<const float4*>(x)[i];
        ushort4 o;
        o.x = f2bf(v.x); o.y = f2bf(v.y); o.z = f2bf(v.z); o.w = f2bf(v.w);
        reinterpret_cast<ushort4*>(y)[i] = o;
    }
}

// ---------------------------------------------------------------------------
__global__ void pack_w_kernel(const float* __restrict__ wr, const float* __restrict__ wi,
                              const float* __restrict__ wj, const float* __restrict__ wk,
                              u16* __restrict__ W) {
    int i = blockIdx.x * blockDim.x + threadIdx.x;
    if (i >= QN * (QK / 4)) return;
    int n = i >> 9;
    int p = i & 511;
    int q = n >> 2, co = n & 3;
    int base = (q << 9) + p;
    float r  = wr[base], ii = wi[base], jj = wj[base], kk = wk[base];
    float e0, e1, e2, e3;
    if      (co == 0) { e0 = r;  e1 = -ii; e2 = -jj; e3 = -kk; }
    else if (co == 1) { e0 = ii; e1 = r;   e2 = -jj; e3 = kk;  }
    else if (co == 2) { e0 = jj; e1 = ii;  e2 = r;   e3 = -kk; }
    else              { e0 = kk; e1 = -ii; e2 = jj;  e3 = r;   }
    ushort4 o;
    o.x = f2bf(e0); o.y = f2bf(e1); o.z = f2bf(e2); o.w = f2bf(e3);
    reinterpret_cast<ushort4*>(W)[(n << 9) + p] = o;
}

// ---------------------------------------------------------------------------
// LDS layout (u16 elems): L[b*32768 + mat*16384 + row*64 + chunkswz*8]
//   physical 16B-chunk (r, cp) holds logical (r, cp ^ (r&7))   [involution]
// Per K-tile t (buffer b = t&1), 4 phases = (ks, m-half):
//   ph0 (ks0,mh0): reads B[*][ks0](4) + A[0..3][ks0](4); stage (t+1,A0)->b^1
//   ph1 (ks0,mh1): reads A[4..7][ks0](4) + B[*][ks1](4);  stage (t+1,A1)->b^1
//   ph2 (ks1,mh0): reads A[0..3][ks1](4);                 stage (t+2,B0)->b
//   ph3 (ks1,mh1): reads A[4..7][ks1](4);                 stage (t+2,B1)->b
//   each: [reads; stage] barrier; lgkmcnt(0); sched_barrier; setprio(1);
//         16 MFMA; setprio(0); [ph3: vmcnt(4)] barrier
// Race-safety: B[ks1] reads complete at ph1's lgkmcnt(0) (all waves), the
//   (t+2,B*) stages issue only after ph1's trailing barrier. A stages go to
//   the opposite buffer. vmcnt(4) at ph3 drains the 8 oldest in-flight loads
//   = all 4 half-tiles of tile t+1; only (t+2,B*) (4 loads) stay in flight.
// ---------------------------------------------------------------------------
__global__ __launch_bounds__(512, 2) void qgemm_kernel(const u16* __restrict__ A,
                                                       const u16* __restrict__ B,
                                                       const float* __restrict__ bias,
                                                       float* __restrict__ C) {
    __shared__ __align__(16) u16 L[2 * 32768];  // 128 KB

    const int bid = blockIdx.x;                 // 512 blocks, %8==0
    const int swz = (bid & 7) * 64 + (bid >> 3);
    const int bm = swz >> 3;                    // 0..63
    const int bn = swz & 7;                     // 0..7

    const int tid = threadIdx.x;
    const int wid = tid >> 6, lane = tid & 63;
    const int wm = wid >> 2, wn = wid & 3;
    const int lr = lane & 15, lg = lane >> 4;

    const u16* Asrc = A + (size_t)bm * 256 * QK;
    const u16* Bsrc = B + (size_t)bn * 256 * QK;

    // staging: half-tile = 128 rows x 64 cols = 1024 chunks of 16B
    const int rA  = tid >> 3;                        // 0..63 (wave covers 8 rows/half)
    const int clA = ((tid & 7) ^ (rA & 7)) << 3;     // pre-swizzled global col
    const size_t soff = (size_t)rA * QK + clA;

    f32x4 acc[8][4];
#pragma unroll
    for (int i = 0; i < 8; ++i)
#pragma unroll
        for (int j = 0; j < 4; ++j)
            acc[i][j] = (f32x4){0.f, 0.f, 0.f, 0.f};

    auto stage = [&](const u16* src, int lbase, int k0) {
#pragma unroll
        for (int o = 0; o < 2; ++o)
            async_copy16(src + (size_t)(o * 64) * QK + k0 + soff,
                         &L[lbase + o * 4096 + wid * 512]);
    };

    // fragment read helpers (read side applies the same XOR as staging)
    auto rdA = [&](const u16* LA, int mf, int ks) -> bf16x8 {
        const int r = wm * 128 + mf * 16 + lr;
        const int c = ((ks * 4 + lg) ^ (r & 7)) << 3;
        return *(const bf16x8*)&LA[r * 64 + c];
    };
    auto rdB = [&](const u16* LB, int nf, int ks) -> bf16x8 {
        const int r = wn * 64 + nf * 16 + lr;
        const int c = ((ks * 4 + lg) ^ (r & 7)) << 3;
        return *(const bf16x8*)&LB[r * 64 + c];
    };

    // prologue: tile0 {A0,A1,B0,B1} -> buf0, tile1 {B0,B1} -> buf1
    stage(Asrc,            0,                 0);
    stage(Asrc + 128 * QK, 8192,              0);
    stage(Bsrc,            16384,             0);
    stage(Bsrc + 128 * QK, 16384 + 8192,      0);
    stage(Bsrc,            32768 + 16384,        64);
    stage(Bsrc + 128 * QK, 32768 + 16384 + 8192, 64);
    asm volatile("s_waitcnt vmcnt(4)" ::: "memory");   // tile0 resident
    __builtin_amdgcn_s_barrier();

    for (int t = 0; t < 32; ++t) {
        const int b = t & 1;
        const u16* LA = &L[b * 32768];
        const u16* LB = LA + 16384;
        const int tw1 = (t + 1) & 31, tw2 = (t + 2) & 31;
        const int ob = (tw1 & 1) * 32768;   // opposite buffer base (A dest)
        const int cb = b * 32768;           // current buffer base (B dest)

        bf16x8 a0[4], a1[4], b0[4], b1[4];

        // ---- phase 0: (ks0, mh0) --------------------------------------
#pragma unroll
        for (int nf = 0; nf < 4; ++nf) b0[nf] = rdB(LB, nf, 0);
#pragma unroll
        for (int mf = 0; mf < 4; ++mf) a0[mf] = rdA(LA, mf, 0);
        stage(Asrc, ob, tw1 * 64);
        __builtin_amdgcn_s_barrier();
        asm volatile("s_waitcnt lgkmcnt(0)" ::: "memory");
        __builtin_amdgcn_sched_barrier(0);
        __builtin_amdgcn_s_setprio(1);
#pragma unroll
        for (int mf = 0; mf < 4; ++mf)
#pragma unroll
            for (int nf = 0; nf < 4; ++nf)
                acc[mf][nf] = __builtin_amdgcn_mfma_f32_16x16x32_bf16(a0[mf], b0[nf], acc[mf][nf], 0, 0, 0);
        __builtin_amdgcn_s_setprio(0);
        __builtin_amdgcn_s_barrier();

        // ---- phase 1: (ks0, mh1) + B[ks1] prefetch-read ----------------
#pragma unroll
        for (int mf = 0; mf < 4; ++mf) a1[mf] = rdA(LA, 4 + mf, 0);
#pragma unroll
        for (int nf = 0; nf < 4; ++nf) b1[nf] = rdB(LB, nf, 1);
        stage(Asrc + 128 * QK, ob + 8192, tw1 * 64);
        __builtin_amdgcn_s_barrier();
        asm volatile("s_waitcnt lgkmcnt(0)" ::: "memory");
        __builtin_amdgcn_sched_barrier(0);
        __builtin_amdgcn_s_setprio(1);
#pragma unroll
        for (int mf = 0; mf < 4; ++mf)
#pragma unroll
            for (int nf = 0; nf < 4; ++nf)
                acc[4 + mf][nf] = __builtin_amdgcn_mfma_f32_16x16x32_bf16(a1[mf], b0[nf], acc[4 + mf][nf], 0, 0, 0);
        __builtin_amdgcn_s_setprio(0);
        __builtin_amdgcn_s_barrier();

        // ---- phase 2: (ks1, mh0) --------------------------------------
#pragma unroll
        for (int mf = 0; mf < 4; ++mf) a0[mf] = rdA(LA, mf, 1);
        stage(Bsrc, cb + 16384, tw2 * 64);
        __builtin_amdgcn_s_barrier();
        asm volatile("s_waitcnt lgkmcnt(0)" ::: "memory");
        __builtin_amdgcn_sched_barrier(0);
        __builtin_amdgcn_s_setprio(1);
#pragma unroll
        for (int mf = 0; mf < 4; ++mf)
#pragma unroll
            for (int nf = 0; nf < 4; ++nf)
                acc[mf][nf] = __builtin_amdgcn_mfma_f32_16x16x32_bf16(a0[mf], b1[nf], acc[mf][nf], 0, 0, 0);
        __builtin_amdgcn_s_setprio(0);
        __builtin_amdgcn_s_barrier();

        // ---- phase 3: (ks1, mh1) --------------------------------------
#pragma unroll
        for (int mf = 0; mf < 4; ++mf) a1[mf] = rdA(LA, 4 + mf, 1);
        stage(Bsrc + 128 * QK, cb + 16384 + 8192, tw2 * 64);
        __builtin_amdgcn_s_barrier();
        asm volatile("s_waitcnt lgkmcnt(0)" ::: "memory");
        __builtin_amdgcn_sched_barrier(0);
        __builtin_amdgcn_s_setprio(1);
#pragma unroll
        for (int mf = 0; mf < 4; ++mf)
#pragma unroll
            for (int nf = 0; nf < 4; ++nf)
                acc[4 + mf][nf] = __builtin_amdgcn_mfma_f32_16x16x32_bf16(a1[mf], b1[nf], acc[4 + mf][nf], 0, 0, 0);
        __builtin_amdgcn_s_setprio(0);
        asm volatile("s_waitcnt vmcnt(4)" ::: "memory");
        __builtin_amdgcn_s_barrier();
    }

    // epilogue: C/D layout col = lane&15, row = (lane>>4)*4 + reg
    const int colbase = bn * 256 + wn * 64;
    const int rowbase = bm * 256 + wm * 128;
    float bsv[4];
#pragma unroll
    for (int nf = 0; nf < 4; ++nf) bsv[nf] = bias[colbase + nf * 16 + lr];
    float* Cb = C + (size_t)rowbase * QN + colbase;
#pragma unroll
    for (int mf = 0; mf < 8; ++mf)
#pragma unroll
        for (int nf = 0; nf < 4; ++nf)
#pragma unroll
            for (int v = 0; v < 4; ++v)
                Cb[(size_t)(mf * 16 + lg * 4 + v) * QN + nf * 16 + lr] = acc[mf][nf][v] + bsv[nf];
}

// ---------------------------------------------------------------------------
extern "C" void kernel_launch(void* const* d_in, const int* in_sizes, int n_in,
                              void* d_out, int out_size, void* d_ws, size_t ws_size,
                              hipStream_t stream) {
    const float* x    = (const float*)d_in[0];
    const float* wr   = (const float*)d_in[1];
    const float* wi   = (const float*)d_in[2];
    const float* wj   = (const float*)d_in[3];
    const float* wk   = (const float*)d_in[4];
    const float* bias = (const float*)d_in[5];
    float* out = (float*)d_out;

    u16* xb = (u16*)d_ws;                                   // 64 MB
    u16* wb = (u16*)((char*)d_ws + (size_t)QM * QK * 2);    // 8 MB

    cvt_x_kernel<<<4096, 256, 0, stream>>>(x, xb, (QM * QK) / 4);
    pack_w_kernel<<<4096, 256, 0, stream>>>(wr, wi, wj, wk, wb);
    qgemm_kernel<<<512, 512, 0, stream>>>(xb, wb, bias, out);
}

// Round 4
// 165.935 us; speedup vs baseline: 1.2159x; 1.0184x over previous
//
#include <hip/hip_runtime.h>

// ---------------------------------------------------------------------------
// QuaternionLinear == one dense GEMM: out[M,N] = x[M,K] @ W_eff[N,K]^T + bias
//   M = 16384 (B*S), N = 2048 (OUT_F), K = 2048 (IN_F)
// Pipeline: cvt_x (fp32->bf16) ; pack_w (build W_eff bf16) ; qgemm (8-phase).
// qgemm: 256x256 tile, BK=64, 8 waves (2x4), per-wave 128x64, 16x16x32 MFMA,
// double-buffered LDS (128 KB), chunk-XOR swizzle (T2), counted vmcnt(4)
// (T3/T4), setprio (T5), XCD swizzle (T1).
// R4: exact m201 sync style — NO sched_barrier, NO memory clobber on the
// per-phase lgkm waits (compiler free to interleave reads/VALU into MFMA
// shadows); single "memory"-clobbered vmcnt(4) per K-tile as the correctness
// anchor; K-loop unrolled 2 tiles/iter so buffer bases are compile-time.
// ---------------------------------------------------------------------------

typedef unsigned short u16;
typedef __bf16 bf16x8 __attribute__((ext_vector_type(8)));
typedef float f32x4 __attribute__((ext_vector_type(4)));

#define QM 16384
#define QN 2048
#define QK 2048

__device__ __forceinline__ u16 f2bf(float f) {
    union { float f; unsigned u; } v;
    v.f = f;
    unsigned r = v.u + 0x7FFFu + ((v.u >> 16) & 1u);
    return (u16)(r >> 16);
}

__device__ __forceinline__ void async_copy16(const u16* g, u16* l) {
    __builtin_amdgcn_global_load_lds(
        (const __attribute__((address_space(1))) void*)g,
        (__attribute__((address_space(3))) void*)l,
        16, 0, 0);
}

// ---------------------------------------------------------------------------
__global__ void cvt_x_kernel(const float* __restrict__ x, u16* __restrict__ y, int n4) {
    for (int i = blockIdx.x * blockDim.x + threadIdx.x; i < n4; i += gridDim.x * blockDim.x) {
        float4 v = reinterpret_cast<const float4*>(x)[i];
        ushort4 o;
        o.x = f2bf(v.x); o.y = f2bf(v.y); o.z = f2bf(v.z); o.w = f2bf(v.w);
        reinterpret_cast<ushort4*>(y)[i] = o;
    }
}

// ---------------------------------------------------------------------------
__global__ void pack_w_kernel(const float* __restrict__ wr, const float* __restrict__ wi,
                              const float* __restrict__ wj, const float* __restrict__ wk,
                              u16* __restrict__ W) {
    int i = blockIdx.x * blockDim.x + threadIdx.x;
    if (i >= QN * (QK / 4)) return;
    int n = i >> 9;
    int p = i & 511;
    int q = n >> 2, co = n & 3;
    int base = (q << 9) + p;
    float r  = wr[base], ii = wi[base], jj = wj[base], kk = wk[base];
    float e0, e1, e2, e3;
    if      (co == 0) { e0 = r;  e1 = -ii; e2 = -jj; e3 = -kk; }
    else if (co == 1) { e0 = ii; e1 = r;   e2 = -jj; e3 = kk;  }
    else if (co == 2) { e0 = jj; e1 = ii;  e2 = r;   e3 = -kk; }
    else              { e0 = kk; e1 = -ii; e2 = jj;  e3 = r;   }
    ushort4 o;
    o.x = f2bf(e0); o.y = f2bf(e1); o.z = f2bf(e2); o.w = f2bf(e3);
    reinterpret_cast<ushort4*>(W)[(n << 9) + p] = o;
}

// ---------------------------------------------------------------------------
// LDS layout (u16 elems): L[b*32768 + mat*16384 + row*64 + chunkswz*8]
//   physical 16B-chunk (r, cp) holds logical (r, cp ^ (r&7))   [involution]
// Per K-tile t (buffer b), 4 phases = (ks, m-half):
//   ph0 (ks0,mh0): reads B[*][ks0](4) + A[0..3][ks0](4); stage (t+1,A0)->b^1
//   ph1 (ks0,mh1): reads A[4..7][ks0](4) + B[*][ks1](4);  stage (t+1,A1)->b^1
//   ph2 (ks1,mh0): reads A[0..3][ks1](4);                 stage (t+2,B0)->b
//   ph3 (ks1,mh1): reads A[4..7][ks1](4);                 stage (t+2,B1)->b
//   each: [reads; stage] barrier; lgkmcnt(0) (no clobber); setprio(1);
//         16 MFMA; setprio(0); [ph3 only: vmcnt(4) w/ "memory"] barrier
// Race-safety: B[ks1] reads complete at ph1's lgkm drain before ph2's stage
//   (loads cannot cross the side-effecting global_load_lds intrinsic; cross-
//   wave ordering via ph1's trailing barrier). A stages target the opposite
//   buffer. vmcnt(4)+clobber at ph3 = tile t+1 fully resident and no next-
//   tile ds_read may hoist above it; only (t+2,B*) (4 loads) stay in flight.
// ---------------------------------------------------------------------------
__global__ __launch_bounds__(512, 2) void qgemm_kernel(const u16* __restrict__ A,
                                                       const u16* __restrict__ B,
                                                       const float* __restrict__ bias,
                                                       float* __restrict__ C) {
    __shared__ __align__(16) u16 L[2 * 32768];  // 128 KB

    const int bid = blockIdx.x;                 // 512 blocks, %8==0
    const int swz = (bid & 7) * 64 + (bid >> 3);
    const int bm = swz >> 3;                    // 0..63
    const int bn = swz & 7;                     // 0..7

    const int tid = threadIdx.x;
    const int wid = tid >> 6, lane = tid & 63;
    const int wm = wid >> 2, wn = wid & 3;
    const int lr = lane & 15, lg = lane >> 4;

    const u16* Asrc = A + (size_t)bm * 256 * QK;
    const u16* Bsrc = B + (size_t)bn * 256 * QK;

    // staging: half-tile = 128 rows x 64 cols = 1024 chunks of 16B
    const int rA  = tid >> 3;                        // 0..63 (wave covers 8 rows/half)
    const int clA = ((tid & 7) ^ (rA & 7)) << 3;     // pre-swizzled global col
    const size_t soff = (size_t)rA * QK + clA;

    f32x4 acc[8][4];
#pragma unroll
    for (int i = 0; i < 8; ++i)
#pragma unroll
        for (int j = 0; j < 4; ++j)
            acc[i][j] = (f32x4){0.f, 0.f, 0.f, 0.f};

    auto stage = [&](const u16* src, int lbase, int k0) {
#pragma unroll
        for (int o = 0; o < 2; ++o)
            async_copy16(src + (size_t)(o * 64) * QK + k0 + soff,
                         &L[lbase + o * 4096 + wid * 512]);
    };

    auto rdA = [&](const u16* LA, int mf, int ks) -> bf16x8 {
        const int r = wm * 128 + mf * 16 + lr;
        const int c = ((ks * 4 + lg) ^ (r & 7)) << 3;
        return *(const bf16x8*)&LA[r * 64 + c];
    };
    auto rdB = [&](const u16* LB, int nf, int ks) -> bf16x8 {
        const int r = wn * 64 + nf * 16 + lr;
        const int c = ((ks * 4 + lg) ^ (r & 7)) << 3;
        return *(const bf16x8*)&LB[r * 64 + c];
    };

    // one K-tile, b = compile-time buffer index (callers pass constants)
    auto doTile = [&](const int b, const int t) __attribute__((always_inline)) {
        const u16* LA = &L[b * 32768];
        const u16* LB = LA + 16384;
        const int tw1 = (t + 1) & 31, tw2 = (t + 2) & 31;
        const int ob = (b ^ 1) * 32768;   // opposite buffer (A dest)
        const int cb = b * 32768;         // current buffer (B dest)

        bf16x8 a0[4], a1[4], b0[4], b1[4];

        // ---- phase 0: (ks0, mh0) --------------------------------------
#pragma unroll
        for (int nf = 0; nf < 4; ++nf) b0[nf] = rdB(LB, nf, 0);
#pragma unroll
        for (int mf = 0; mf < 4; ++mf) a0[mf] = rdA(LA, mf, 0);
        stage(Asrc, ob, tw1 * 64);
        __builtin_amdgcn_s_barrier();
        asm volatile("s_waitcnt lgkmcnt(0)");
        __builtin_amdgcn_s_setprio(1);
#pragma unroll
        for (int mf = 0; mf < 4; ++mf)
#pragma unroll
            for (int nf = 0; nf < 4; ++nf)
                acc[mf][nf] = __builtin_amdgcn_mfma_f32_16x16x32_bf16(a0[mf], b0[nf], acc[mf][nf], 0, 0, 0);
        __builtin_amdgcn_s_setprio(0);
        __builtin_amdgcn_s_barrier();

        // ---- phase 1: (ks0, mh1) + B[ks1] prefetch-read ----------------
#pragma unroll
        for (int mf = 0; mf < 4; ++mf) a1[mf] = rdA(LA, 4 + mf, 0);
#pragma unroll
        for (int nf = 0; nf < 4; ++nf) b1[nf] = rdB(LB, nf, 1);
        stage(Asrc + 128 * QK, ob + 8192, tw1 * 64);
        __builtin_amdgcn_s_barrier();
        asm volatile("s_waitcnt lgkmcnt(0)");
        __builtin_amdgcn_s_setprio(1);
#pragma unroll
        for (int mf = 0; mf < 4; ++mf)
#pragma unroll
            for (int nf = 0; nf < 4; ++nf)
                acc[4 + mf][nf] = __builtin_amdgcn_mfma_f32_16x16x32_bf16(a1[mf], b0[nf], acc[4 + mf][nf], 0, 0, 0);
        __builtin_amdgcn_s_setprio(0);
        __builtin_amdgcn_s_barrier();

        // ---- phase 2: (ks1, mh0) --------------------------------------
#pragma unroll
        for (int mf = 0; mf < 4; ++mf) a0[mf] = rdA(LA, mf, 1);
        stage(Bsrc, cb + 16384, tw2 * 64);
        __builtin_amdgcn_s_barrier();
        asm volatile("s_waitcnt lgkmcnt(0)");
        __builtin_amdgcn_s_setprio(1);
#pragma unroll
        for (int mf = 0; mf < 4; ++mf)
#pragma unroll
            for (int nf = 0; nf < 4; ++nf)
                acc[mf][nf] = __builtin_amdgcn_mfma_f32_16x16x32_bf16(a0[mf], b1[nf], acc[mf][nf], 0, 0, 0);
        __builtin_amdgcn_s_setprio(0);
        __builtin_amdgcn_s_barrier();

        // ---- phase 3: (ks1, mh1) --------------------------------------
#pragma unroll
        for (int mf = 0; mf < 4; ++mf) a1[mf] = rdA(LA, 4 + mf, 1);
        stage(Bsrc + 128 * QK, cb + 16384 + 8192, tw2 * 64);
        __builtin_amdgcn_s_barrier();
        asm volatile("s_waitcnt lgkmcnt(0)");
        __builtin_amdgcn_s_setprio(1);
#pragma unroll
        for (int mf = 0; mf < 4; ++mf)
#pragma unroll
            for (int nf = 0; nf < 4; ++nf)
                acc[4 + mf][nf] = __builtin_amdgcn_mfma_f32_16x16x32_bf16(a1[mf], b1[nf], acc[4 + mf][nf], 0, 0, 0);
        __builtin_amdgcn_s_setprio(0);
        asm volatile("s_waitcnt vmcnt(4)" ::: "memory");  // tile t+1 resident; pins next-tile reads
        __builtin_amdgcn_s_barrier();
    };

    // prologue: tile0 {A0,A1,B0,B1} -> buf0, tile1 {B0,B1} -> buf1
    stage(Asrc,            0,                 0);
    stage(Asrc + 128 * QK, 8192,              0);
    stage(Bsrc,            16384,             0);
    stage(Bsrc + 128 * QK, 16384 + 8192,      0);
    stage(Bsrc,            32768 + 16384,        64);
    stage(Bsrc + 128 * QK, 32768 + 16384 + 8192, 64);
    asm volatile("s_waitcnt vmcnt(4)" ::: "memory");   // tile0 resident
    __builtin_amdgcn_s_barrier();

    for (int t = 0; t < 32; t += 2) {
        doTile(0, t);
        doTile(1, t + 1);
    }

    // epilogue: C/D layout col = lane&15, row = (lane>>4)*4 + reg
    const int colbase = bn * 256 + wn * 64;
    const int rowbase = bm * 256 + wm * 128;
    float bsv[4];
#pragma unroll
    for (int nf = 0; nf < 4; ++nf) bsv[nf] = bias[colbase + nf * 16 + lr];
    float* Cb = C + (size_t)rowbase * QN + colbase;
#pragma unroll
    for (int mf = 0; mf < 8; ++mf)
#pragma unroll
        for (int nf = 0; nf < 4; ++nf)
#pragma unroll
            for (int v = 0; v < 4; ++v)
                Cb[(size_t)(mf * 16 + lg * 4 + v) * QN + nf * 16 + lr] = acc[mf][nf][v] + bsv[nf];
}

// ---------------------------------------------------------------------------
extern "C" void kernel_launch(void* const* d_in, const int* in_sizes, int n_in,
                              void* d_out, int out_size, void* d_ws, size_t ws_size,
                              hipStream_t stream) {
    const float* x    = (const float*)d_in[0];
    const float* wr   = (const float*)d_in[1];
    const float* wi   = (const float*)d_in[2];
    const float* wj   = (const float*)d_in[3];
    const float* wk   = (const float*)d_in[4];
    const float* bias = (const float*)d_in[5];
    float* out = (float*)d_out;

    u16* xb = (u16*)d_ws;                                   // 64 MB
    u16* wb = (u16*)((char*)d_ws + (size_t)QM * QK * 2);    // 8 MB

    cvt_x_kernel<<<4096, 256, 0, stream>>>(x, xb, (QM * QK) / 4);
    pack_w_kernel<<<4096, 256, 0, stream>>>(wr, wi, wj, wk, wb);
    qgemm_kernel<<<512, 512, 0, stream>>>(xb, wb, bias, out);
}

// Round 5
// 162.480 us; speedup vs baseline: 1.2418x; 1.0213x over previous
//
#include <hip/hip_runtime.h>

// ---------------------------------------------------------------------------
// QuaternionLinear == one dense GEMM: out[M,N] = x[M,K] @ W_eff[N,K]^T + bias
//   M = 16384 (B*S), N = 2048 (OUT_F), K = 2048 (IN_F)
// Pipeline: cvt_x (fp32->bf16) ; pack_w (build W_eff bf16) ; qgemm.
// qgemm: 256x256 tile, BK=64, 8 waves (2x4), per-wave 128x64, 16x16x32 MFMA,
// double-buffered LDS (128 KB), chunk-XOR swizzle (T2), counted vmcnt(4)
// (T3/T4), setprio (T5), XCD swizzle (T1).
// R5: minimal-barrier schedule — only the 2 sync points per K-tile that the
// race analysis requires (mid: B-reads drained before B-stage; end: buffer
// swap). The removed 6 barriers/tile only enforced lockstep, which
// serialized the LDS pipe (~2300 cyc/tile/CU) against the MFMA pipe
// (~2480 cyc/tile/CU). With waves free to drift between sync points, the
// two pipes overlap (m114 mechanism).
// ---------------------------------------------------------------------------

typedef unsigned short u16;
typedef __bf16 bf16x8 __attribute__((ext_vector_type(8)));
typedef float f32x4 __attribute__((ext_vector_type(4)));

#define QM 16384
#define QN 2048
#define QK 2048

__device__ __forceinline__ u16 f2bf(float f) {
    union { float f; unsigned u; } v;
    v.f = f;
    unsigned r = v.u + 0x7FFFu + ((v.u >> 16) & 1u);
    return (u16)(r >> 16);
}

__device__ __forceinline__ void async_copy16(const u16* g, u16* l) {
    __builtin_amdgcn_global_load_lds(
        (const __attribute__((address_space(1))) void*)g,
        (__attribute__((address_space(3))) void*)l,
        16, 0, 0);
}

// ---------------------------------------------------------------------------
__global__ void cvt_x_kernel(const float* __restrict__ x, u16* __restrict__ y, int n4) {
    for (int i = blockIdx.x * blockDim.x + threadIdx.x; i < n4; i += gridDim.x * blockDim.x) {
        float4 v = reinterpret_cast<const float4*>(x)[i];
        ushort4 o;
        o.x = f2bf(v.x); o.y = f2bf(v.y); o.z = f2bf(v.z); o.w = f2bf(v.w);
        reinterpret_cast<ushort4*>(y)[i] = o;
    }
}

// ---------------------------------------------------------------------------
__global__ void pack_w_kernel(const float* __restrict__ wr, const float* __restrict__ wi,
                              const float* __restrict__ wj, const float* __restrict__ wk,
                              u16* __restrict__ W) {
    int i = blockIdx.x * blockDim.x + threadIdx.x;
    if (i >= QN * (QK / 4)) return;
    int n = i >> 9;
    int p = i & 511;
    int q = n >> 2, co = n & 3;
    int base = (q << 9) + p;
    float r  = wr[base], ii = wi[base], jj = wj[base], kk = wk[base];
    float e0, e1, e2, e3;
    if      (co == 0) { e0 = r;  e1 = -ii; e2 = -jj; e3 = -kk; }
    else if (co == 1) { e0 = ii; e1 = r;   e2 = -jj; e3 = kk;  }
    else if (co == 2) { e0 = jj; e1 = ii;  e2 = r;   e3 = -kk; }
    else              { e0 = kk; e1 = -ii; e2 = jj;  e3 = r;   }
    ushort4 o;
    o.x = f2bf(e0); o.y = f2bf(e1); o.z = f2bf(e2); o.w = f2bf(e3);
    reinterpret_cast<ushort4*>(W)[(n << 9) + p] = o;
}

// ---------------------------------------------------------------------------
// LDS layout (u16 elems): L[b*32768 + mat*16384 + row*64 + chunkswz*8]
//   physical 16B-chunk (r, cp) holds logical (r, cp ^ (r&7))   [involution]
// Per K-tile t (buffer b), 2 sync points:
//   [tile start: buf b fully resident (prev vmcnt), all prior reads drained]
//   reads b0,a0,a1,b1 (16); stage A0(t+1)->b^1; MFMA(a0xb0); stage A1->b^1;
//   MFMA(a1xb0);
//   lgkmcnt(0) ["memory"]; BARRIER        <- all waves' B reads (b0,b1) done
//   reads a0'(ks1); stage B0(t+2)->b; MFMA(a0'xb1); reads a1'(ks1);
//   stage B1(t+2)->b; MFMA(a1'xb1);
//   lgkmcnt(0); vmcnt(4) ["memory"]; BARRIER   <- tile t+1 resident; all
//                                                 tile-t reads drained
// Race-safety:
//   - B(t+2)->b stages issue only after the mid barrier, which follows a
//     clobbered lgkm(0): every wave's b0/b1 reads are complete.   [1]
//   - A(t+1)->b^1 stages: b^1's A-region reads finished at tile t-1's end
//     drain; residency for tile t+1 via end vmcnt(4).              [2]
//   - A-region reads of buf b (a0',a1' after mid barrier) vs A(t+2) stages:
//     those issue in tile t+1 after the end barrier + end drain.   [3]
//   - vmcnt(4) at end: in-flight queue [B(t+1)x4, A(t+1)x4, B(t+2)x4];
//     wait to 4 => A(t+1),B(t+1) resident; B(t+2) stays in flight. [4]
// ---------------------------------------------------------------------------
__global__ __launch_bounds__(512, 2) void qgemm_kernel(const u16* __restrict__ A,
                                                       const u16* __restrict__ B,
                                                       const float* __restrict__ bias,
                                                       float* __restrict__ C) {
    __shared__ __align__(16) u16 L[2 * 32768];  // 128 KB

    const int bid = blockIdx.x;                 // 512 blocks, %8==0
    const int swz = (bid & 7) * 64 + (bid >> 3);
    const int bm = swz >> 3;                    // 0..63
    const int bn = swz & 7;                     // 0..7

    const int tid = threadIdx.x;
    const int wid = tid >> 6, lane = tid & 63;
    const int wm = wid >> 2, wn = wid & 3;
    const int lr = lane & 15, lg = lane >> 4;

    const u16* Asrc = A + (size_t)bm * 256 * QK;
    const u16* Bsrc = B + (size_t)bn * 256 * QK;

    // staging: half-tile = 128 rows x 64 cols = 1024 chunks of 16B
    const int rA  = tid >> 3;                        // 0..63 (wave covers 8 rows/half)
    const int clA = ((tid & 7) ^ (rA & 7)) << 3;     // pre-swizzled global col
    const size_t soff = (size_t)rA * QK + clA;

    f32x4 acc[8][4];
#pragma unroll
    for (int i = 0; i < 8; ++i)
#pragma unroll
        for (int j = 0; j < 4; ++j)
            acc[i][j] = (f32x4){0.f, 0.f, 0.f, 0.f};

    auto stage = [&](const u16* src, int lbase, int k0) {
#pragma unroll
        for (int o = 0; o < 2; ++o)
            async_copy16(src + (size_t)(o * 64) * QK + k0 + soff,
                         &L[lbase + o * 4096 + wid * 512]);
    };

    auto rdA = [&](const u16* LA, int mf, int ks) -> bf16x8 {
        const int r = wm * 128 + mf * 16 + lr;
        const int c = ((ks * 4 + lg) ^ (r & 7)) << 3;
        return *(const bf16x8*)&LA[r * 64 + c];
    };
    auto rdB = [&](const u16* LB, int nf, int ks) -> bf16x8 {
        const int r = wn * 64 + nf * 16 + lr;
        const int c = ((ks * 4 + lg) ^ (r & 7)) << 3;
        return *(const bf16x8*)&LB[r * 64 + c];
    };

    auto doTile = [&](const int b, const int t) __attribute__((always_inline)) {
        const u16* LA = &L[b * 32768];
        const u16* LB = LA + 16384;
        const int tw1 = (t + 1) & 31, tw2 = (t + 2) & 31;
        const int ob = (b ^ 1) * 32768;   // opposite buffer (A dest)
        const int cb = b * 32768;         // current buffer (B dest)

        bf16x8 a0[4], a1[4], b0[4], b1[4];

        // ---- first half-tile (ks0), no interior barriers ----------------
#pragma unroll
        for (int nf = 0; nf < 4; ++nf) b0[nf] = rdB(LB, nf, 0);
#pragma unroll
        for (int mf = 0; mf < 4; ++mf) a0[mf] = rdA(LA, mf, 0);
        stage(Asrc, ob, tw1 * 64);
        __builtin_amdgcn_s_setprio(1);
#pragma unroll
        for (int mf = 0; mf < 4; ++mf)
#pragma unroll
            for (int nf = 0; nf < 4; ++nf)
                acc[mf][nf] = __builtin_amdgcn_mfma_f32_16x16x32_bf16(a0[mf], b0[nf], acc[mf][nf], 0, 0, 0);
        __builtin_amdgcn_s_setprio(0);
#pragma unroll
        for (int mf = 0; mf < 4; ++mf) a1[mf] = rdA(LA, 4 + mf, 0);
#pragma unroll
        for (int nf = 0; nf < 4; ++nf) b1[nf] = rdB(LB, nf, 1);
        stage(Asrc + 128 * QK, ob + 8192, tw1 * 64);
        __builtin_amdgcn_s_setprio(1);
#pragma unroll
        for (int mf = 0; mf < 4; ++mf)
#pragma unroll
            for (int nf = 0; nf < 4; ++nf)
                acc[4 + mf][nf] = __builtin_amdgcn_mfma_f32_16x16x32_bf16(a1[mf], b0[nf], acc[4 + mf][nf], 0, 0, 0);
        __builtin_amdgcn_s_setprio(0);

        // ---- sync point 1: all waves' B reads drained --------------------
        asm volatile("s_waitcnt lgkmcnt(0)" ::: "memory");
        __builtin_amdgcn_s_barrier();

        // ---- second half-tile (ks1) --------------------------------------
#pragma unroll
        for (int mf = 0; mf < 4; ++mf) a0[mf] = rdA(LA, mf, 1);
        stage(Bsrc, cb + 16384, tw2 * 64);
        __builtin_amdgcn_s_setprio(1);
#pragma unroll
        for (int mf = 0; mf < 4; ++mf)
#pragma unroll
            for (int nf = 0; nf < 4; ++nf)
                acc[mf][nf] = __builtin_amdgcn_mfma_f32_16x16x32_bf16(a0[mf], b1[nf], acc[mf][nf], 0, 0, 0);
        __builtin_amdgcn_s_setprio(0);
#pragma unroll
        for (int mf = 0; mf < 4; ++mf) a1[mf] = rdA(LA, 4 + mf, 1);
        stage(Bsrc + 128 * QK, cb + 16384 + 8192, tw2 * 64);
        __builtin_amdgcn_s_setprio(1);
#pragma unroll
        for (int mf = 0; mf < 4; ++mf)
#pragma unroll
            for (int nf = 0; nf < 4; ++nf)
                acc[4 + mf][nf] = __builtin_amdgcn_mfma_f32_16x16x32_bf16(a1[mf], b1[nf], acc[4 + mf][nf], 0, 0, 0);
        __builtin_amdgcn_s_setprio(0);

        // ---- sync point 2: tile t+1 resident, all tile-t reads drained ---
        asm volatile("s_waitcnt lgkmcnt(0) vmcnt(4)" ::: "memory");
        __builtin_amdgcn_s_barrier();
    };

    // prologue: tile0 {A0,A1,B0,B1} -> buf0, tile1 {B0,B1} -> buf1
    stage(Asrc,            0,                 0);
    stage(Asrc + 128 * QK, 8192,              0);
    stage(Bsrc,            16384,             0);
    stage(Bsrc + 128 * QK, 16384 + 8192,      0);
    stage(Bsrc,            32768 + 16384,        64);
    stage(Bsrc + 128 * QK, 32768 + 16384 + 8192, 64);
    asm volatile("s_waitcnt vmcnt(4)" ::: "memory");   // tile0 resident
    __builtin_amdgcn_s_barrier();

    for (int t = 0; t < 32; t += 2) {
        doTile(0, t);
        doTile(1, t + 1);
    }

    // epilogue: C/D layout col = lane&15, row = (lane>>4)*4 + reg
    const int colbase = bn * 256 + wn * 64;
    const int rowbase = bm * 256 + wm * 128;
    float bsv[4];
#pragma unroll
    for (int nf = 0; nf < 4; ++nf) bsv[nf] = bias[colbase + nf * 16 + lr];
    float* Cb = C + (size_t)rowbase * QN + colbase;
#pragma unroll
    for (int mf = 0; mf < 8; ++mf)
#pragma unroll
        for (int nf = 0; nf < 4; ++nf)
#pragma unroll
            for (int v = 0; v < 4; ++v)
                Cb[(size_t)(mf * 16 + lg * 4 + v) * QN + nf * 16 + lr] = acc[mf][nf][v] + bsv[nf];
}

// ---------------------------------------------------------------------------
extern "C" void kernel_launch(void* const* d_in, const int* in_sizes, int n_in,
                              void* d_out, int out_size, void* d_ws, size_t ws_size,
                              hipStream_t stream) {
    const float* x    = (const float*)d_in[0];
    const float* wr   = (const float*)d_in[1];
    const float* wi   = (const float*)d_in[2];
    const float* wj   = (const float*)d_in[3];
    const float* wk   = (const float*)d_in[4];
    const float* bias = (const float*)d_in[5];
    float* out = (float*)d_out;

    u16* xb = (u16*)d_ws;                                   // 64 MB
    u16* wb = (u16*)((char*)d_ws + (size_t)QM * QK * 2);    // 8 MB

    cvt_x_kernel<<<4096, 256, 0, stream>>>(x, xb, (QM * QK) / 4);
    pack_w_kernel<<<4096, 256, 0, stream>>>(wr, wi, wj, wk, wb);
    qgemm_kernel<<<512, 512, 0, stream>>>(xb, wb, bias, out);
}